// Round 21
// baseline (151.848 us; speedup 1.0000x reference)
//
#include <hip/hip_runtime.h>

// 192^3 structure tensor, fused z-streaming pipeline (4 dispatches):
//   S0: setup_coef        (extract 1D rank-1 factors from the provided 3D kernels)
//   S1: blur3d_s1_db<8>   x -> xs    (32x16 tile, float2 yconv, dbuf; 1728 blk = 6.75/CU)
//   S2: grad3d_db<8>      xs -> G[3] (dbuf; 1728 blk = 6.75/CU)
//   S3: blur3d_db<24,6>   G -> out   (products at staging + dbuf; 1728 blk = 6.75/CU)
// r19/r20 law: under the dbuf schedule, occupancy beats z-halo work at ~3:1.
// All three kernels now at 6.75 blocks/CU (wave cap 8, LDS caps 7-12 — not binding).
// Proven LDS classes only: stride-41 b32 staging/sliding windows; stride-32 b128 xt
// (exact 8-row x 8-quad 1-row/thread map); float2/float4 stride-32 reads (1 row/thread).

constexpr int D  = 192;
constexpr int DD = D * D;                  // 36864
constexpr long long V = (long long)D * DD; // 7077888

// coef layout (floats):
//  [0..6] ga  [7..13] gb  [14..20] gc   (gauss z,y,x)
//  [21..29] az (9)  [30..34] bz (5)  [35..39] cz (5)
//  [40..44] ay (5)  [45..53] by (9)  [54..58] cy (5, dup)
//  [59..63] ax (5)  [64..68] bx (5)  [69..77] cx (9)
__global__ void setup_coef(const float* __restrict__ g3, const float* __restrict__ kz,
                           const float* __restrict__ ky, const float* __restrict__ kx,
                           float* __restrict__ c) {
    if (blockIdx.x != 0 || threadIdx.x != 0) return;
    float Tg = g3[0];
    for (int i = 0; i < 7; ++i) c[0 + i]  = g3[i * 49];
    for (int j = 0; j < 7; ++j) c[7 + j]  = g3[j * 7] / Tg;
    for (int k = 0; k < 7; ++k) c[14 + k] = g3[k] / Tg;
    float Tz = kz[0];                      // kz: [9,5,5]
    for (int i = 0; i < 9; ++i) c[21 + i] = kz[i * 25];
    for (int j = 0; j < 5; ++j) c[30 + j] = kz[j * 5] / Tz;
    for (int k = 0; k < 5; ++k) c[35 + k] = kz[k] / Tz;
    float Ty = ky[0];                      // ky: [5,9,5]
    for (int i = 0; i < 5; ++i) c[40 + i] = ky[i * 45];
    for (int j = 0; j < 9; ++j) c[45 + j] = ky[j * 5] / Ty;
    for (int k = 0; k < 5; ++k) c[54 + k] = ky[k] / Ty;
    float Tx = kx[0];                      // kx: [5,5,9]
    for (int i = 0; i < 5; ++i) c[59 + i] = kx[i * 45];
    for (int j = 0; j < 5; ++j) c[64 + j] = kx[j * 9] / Tx;
    for (int k = 0; k < 9; ++k) c[69 + k] = kx[k] / Tx;
}

// Bounds-checked float4 load from one z-slice (row gy, cols gx..gx+3), zero-padded.
__device__ inline float4 ldg4(const float* __restrict__ slice, int gy, int gx) {
    float4 v = {0.f, 0.f, 0.f, 0.f};
    if ((unsigned)gy < (unsigned)D) {
        const float* row = slice + gy * D;
        if ((unsigned)gx <= (unsigned)(D - 4)) {
            v = *(const float4*)(row + gx);
        } else {
            float* pv = (float*)&v;
#pragma unroll
            for (int j = 0; j < 4; ++j) {
                const int g = gx + j;
                if ((unsigned)g < (unsigned)D) pv[j] = row[g];
            }
        }
    }
    return v;
}

// Dual-field bounds-hoisted load: computes bounds once, loads A and B rows.
__device__ inline void ldg4x2(const float* __restrict__ slA, const float* __restrict__ slB,
                              int gy, int gx, float4& a, float4& b) {
    a = make_float4(0.f, 0.f, 0.f, 0.f);
    b = a;
    if ((unsigned)gy < (unsigned)D) {
        const int ro = gy * D;
        if ((unsigned)gx <= (unsigned)(D - 4)) {
            a = *(const float4*)(slA + ro + gx);
            b = *(const float4*)(slB + ro + gx);
        } else {
            float* pa = (float*)&a;
            float* pb = (float*)&b;
#pragma unroll
            for (int j = 0; j < 4; ++j) {
                const int g = gx + j;
                if ((unsigned)g < (unsigned)D) { pa[j] = slA[ro + g]; pb[j] = slB[ro + g]; }
            }
        }
    }
}

// Staging task li -> (row li/10, quad li%10) of a (rows x 40) region, stride-41 LDS.
__device__ inline float4 ld_task10(const float* __restrict__ slice, int y0, int x0, int li) {
    const int r = li / 10, q = li % 10;
    return ldg4(slice, y0 + r, x0 + q * 4);
}
__device__ inline void st_task41(float* __restrict__ dst, int li, float4 v) {
    const int r = li / 10, q = li % 10;
    float* d = &dst[r * 41 + q * 4];
    d[0] = v.x; d[1] = v.y; d[2] = v.z; d[3] = v.w;   // b32 class: conflict-free
}

// Stage one slice of (38 x 40) region into stride-41 LDS, with optional product fusion.
template <bool PROD>
__device__ inline void stage_s3(const float* __restrict__ slA, const float* __restrict__ slB,
                                bool same, float* __restrict__ dst, int ty0, int tx0) {
    if (same) {
        for (int li = threadIdx.x; li < 380; li += 256) {
            float4 a = ld_task10(slA, ty0 - 3, tx0 - 4, li);
            if (PROD) { a.x *= a.x; a.y *= a.y; a.z *= a.z; a.w *= a.w; }
            st_task41(dst, li, a);
        }
    } else {
        for (int li = threadIdx.x; li < 380; li += 256) {
            const int r = li / 10, q = li % 10;
            float4 a, b;
            ldg4x2(slA, slB, ty0 - 3 + r, tx0 - 4 + q * 4, a, b);
            a.x *= b.x; a.y *= b.y; a.z *= b.z; a.w *= b.w;
            float* d = &dst[r * 41 + q * 4];
            d[0] = a.x; d[1] = a.y; d[2] = a.z; d[3] = a.w;
        }
    }
}

// ---- S1: fused separable 3D blur, 32x16 tile, float2 yconv, double-buffered ----
template <int SEG>
__global__ __launch_bounds__(256) void blur3d_s1_db(const float* __restrict__ in,
                                                    float* __restrict__ out,
                                                    const float* __restrict__ coef) {
    __shared__ float raw[2][22 * 41];
    __shared__ float xt[2][22][32];
    const int cpx = gridDim.x >> 3;
    int w = (blockIdx.x & 7) * cpx + (blockIdx.x >> 3);
    const int tile = w % 72;
    const int seg = w / 72;
    const int tx0 = (tile % 6) * 32, ty0 = (tile / 6) * 16;
    const int z0 = seg * SEG;
    float ga[7], gb[7], gc[7];
#pragma unroll
    for (int k = 0; k < 7; ++k) { ga[k] = coef[k]; gb[k] = coef[7 + k]; gc[k] = coef[14 + k]; }
    const int tid = threadIdx.x;
    const int rr = tid >> 4;                   // 0..15 (yconv rows)
    const int cc = (tid & 15) * 2;             // 0,2,..,30
    float2 ring[7];
#pragma unroll
    for (int k = 0; k < 7; ++k) ring[k] = make_float2(0.f, 0.f);

    // prologue: stage first slice into raw[0]
    {
        const int s0 = z0 - 3;
        if (s0 >= 0 && s0 < D && tid < 220)
            st_task41(raw[0], tid, ld_task10(in + (long long)s0 * DD, ty0 - 3, tx0 - 4, tid));
    }
    __syncthreads();

    int cur = 0;
    for (int s = z0 - 3; s < z0 + SEG + 3; ++s) {
        const bool inz = (s >= 0 && s < D);
        if (inz && tid < 176) {
            const int r = tid >> 3, g = tid & 7;
            const float* rp = &raw[cur][r * 41 + 4 * g + 1];
            float win[10];
#pragma unroll
            for (int i = 0; i < 10; ++i) win[i] = rp[i];
            float4 o = make_float4(0.f, 0.f, 0.f, 0.f);
#pragma unroll
            for (int k = 0; k < 7; ++k) {
                o.x += gc[k] * win[k];
                o.y += gc[k] * win[k + 1];
                o.z += gc[k] * win[k + 2];
                o.w += gc[k] * win[k + 3];
            }
            *(float4*)&xt[cur][r][4 * g] = o;
        }
        const int sn = s + 1;
        if (sn < z0 + SEG + 3 && sn >= 0 && sn < D && tid < 220)
            st_task41(raw[cur ^ 1], tid, ld_task10(in + (long long)sn * DD, ty0 - 3, tx0 - 4, tid));
        __syncthreads();                       // xt[cur] + raw[cur^1] ready
        float2 yv = make_float2(0.f, 0.f);
        if (inz) {
#pragma unroll
            for (int k = 0; k < 7; ++k) {
                const float2 v = *(const float2*)&xt[cur][rr + k][cc];
                yv.x += gb[k] * v.x; yv.y += gb[k] * v.y;
            }
        }
#pragma unroll
        for (int k = 0; k < 6; ++k) ring[k] = ring[k + 1];
        ring[6] = yv;
        const int z = s - 3;
        if (z >= z0) {
            float2 a = make_float2(0.f, 0.f);
#pragma unroll
            for (int k = 0; k < 7; ++k) {
                a.x += ga[k] * ring[k].x; a.y += ga[k] * ring[k].y;
            }
            *(float2*)(out + (long long)z * DD + (ty0 + rr) * D + tx0 + cc) = a;
        }
        cur ^= 1;
    }
}

// ---- S3: double-buffered product blur, 32x32 tile, 1 barrier/slice (r16-proven) ----
template <int SEG, int NCH, bool PROD>
__global__ __launch_bounds__(256) void blur3d_db(const float* __restrict__ in,
                                                 float* __restrict__ out,
                                                 const float* __restrict__ coef) {
    __shared__ float raw[2][38 * 41];
    __shared__ float xt[2][38][32];
    const int cpx = gridDim.x >> 3;
    int w = (blockIdx.x & 7) * cpx + (blockIdx.x >> 3);
    const int tile = w % 36; w /= 36;
    const int ch = w % NCH;
    const int seg = w / NCH;
    const int tx0 = (tile % 6) * 32, ty0 = (tile / 6) * 32;
    const int z0 = seg * SEG;
    // product channel -> gradient-field pair: [Jzz,Jzy,Jzx,Jyy,Jyx,Jxx]
    const int IA[6] = {0, 1, 2, 1, 2, 2};
    const int IB[6] = {0, 0, 0, 1, 1, 2};
    const float* srcA = in + (long long)(PROD ? IA[ch] : ch) * V;
    const float* srcB = in + (long long)(PROD ? IB[ch] : ch) * V;
    const bool same = !PROD || (IA[ch] == IB[ch]);
    float* dst = out + (long long)ch * V;
    float ga[7], gb[7], gc[7];
#pragma unroll
    for (int k = 0; k < 7; ++k) { ga[k] = coef[k]; gb[k] = coef[7 + k]; gc[k] = coef[14 + k]; }
    const int tid = threadIdx.x;
    const int rr = tid >> 3;                  // 0..31
    const int cc = (tid & 7) * 4;             // 0,4,..,28
    float4 ring[7];
#pragma unroll
    for (int k = 0; k < 7; ++k) ring[k] = make_float4(0.f, 0.f, 0.f, 0.f);

    // prologue: stage first slice into raw[0]
    {
        const int s0 = z0 - 3;
        if (s0 >= 0 && s0 < D)
            stage_s3<PROD>(srcA + (long long)s0 * DD, srcB + (long long)s0 * DD,
                           same, raw[0], ty0, tx0);
    }
    __syncthreads();

    int cur = 0;
    for (int s = z0 - 3; s < z0 + SEG + 3; ++s) {
        const bool inz = (s >= 0 && s < D);
        // phase a: xconv slice s from raw[cur] into xt[cur]
        if (inz) {
            for (int li = tid; li < 38 * 8; li += 256) {
                const int r = li >> 3, g = li & 7;
                const float* rp = &raw[cur][r * 41 + 4 * g + 1];
                float win[10];
#pragma unroll
                for (int i = 0; i < 10; ++i) win[i] = rp[i];
                float4 o = make_float4(0.f, 0.f, 0.f, 0.f);
#pragma unroll
                for (int k = 0; k < 7; ++k) {
                    o.x += gc[k] * win[k];
                    o.y += gc[k] * win[k + 1];
                    o.z += gc[k] * win[k + 2];
                    o.w += gc[k] * win[k + 3];
                }
                *(float4*)&xt[cur][r][4 * g] = o;
            }
        }
        // phase b: stage slice s+1 into raw[cur^1]
        const int sn = s + 1;
        if (sn < z0 + SEG + 3 && sn >= 0 && sn < D)
            stage_s3<PROD>(srcA + (long long)sn * DD, srcB + (long long)sn * DD,
                           same, raw[cur ^ 1], ty0, tx0);
        __syncthreads();                      // xt[cur] + raw[cur^1] ready
        // phase d: yconv slice s from xt[cur], ring, store
        float4 yv = make_float4(0.f, 0.f, 0.f, 0.f);
        if (inz) {
#pragma unroll
            for (int k = 0; k < 7; ++k) {
                const float4 v = *(const float4*)&xt[cur][rr + k][cc];
                yv.x += gb[k] * v.x; yv.y += gb[k] * v.y;
                yv.z += gb[k] * v.z; yv.w += gb[k] * v.w;
            }
        }
#pragma unroll
        for (int k = 0; k < 6; ++k) ring[k] = ring[k + 1];
        ring[6] = yv;
        const int z = s - 3;
        if (z >= z0) {
            float4 a = make_float4(0.f, 0.f, 0.f, 0.f);
#pragma unroll
            for (int k = 0; k < 7; ++k) {
                a.x += ga[k] * ring[k].x; a.y += ga[k] * ring[k].y;
                a.z += ga[k] * ring[k].z; a.w += ga[k] * ring[k].w;
            }
            *(float4*)(dst + (long long)z * DD + (ty0 + rr) * D + tx0 + cc) = a;
        }
        cur ^= 1;
    }
}

// ---- S2: fused gradients, 32x16 tile, register rings, double-buffered ----
template <int SEG>
__global__ __launch_bounds__(256) void grad3d_db(const float* __restrict__ xs,
                                                 float* __restrict__ G,
                                                 const float* __restrict__ coef) {
    __shared__ float raw[2][24 * 41];
    __shared__ float X1[2][24][32];
    __shared__ float X2[2][24][32];
    const int cpx = gridDim.x >> 3;
    int w = (blockIdx.x & 7) * cpx + (blockIdx.x >> 3);
    const int tile = w % 72;
    const int seg = w / 72;
    const int tx0 = (tile % 6) * 32, ty0 = (tile / 6) * 16;
    const int z0 = seg * SEG;
    float az[9], ay[5], ax[5], bz[5], by[9], bx[5], czc[5], cxc[9];
#pragma unroll
    for (int k = 0; k < 9; ++k) az[k] = coef[21 + k];
#pragma unroll
    for (int k = 0; k < 5; ++k) ay[k] = coef[40 + k];
#pragma unroll
    for (int k = 0; k < 5; ++k) ax[k] = coef[59 + k];
#pragma unroll
    for (int k = 0; k < 5; ++k) bz[k] = coef[30 + k];
#pragma unroll
    for (int k = 0; k < 9; ++k) by[k] = coef[45 + k];
#pragma unroll
    for (int k = 0; k < 5; ++k) bx[k] = coef[64 + k];
#pragma unroll
    for (int k = 0; k < 5; ++k) czc[k] = coef[35 + k];
#pragma unroll
    for (int k = 0; k < 9; ++k) cxc[k] = coef[69 + k];
    const int tid = threadIdx.x;
    const int rr = tid >> 4;                   // 0..15
    const int cc = (tid & 15) * 2;             // 0,2,..,30
    float2 R1[9], R2[7], R3[7];
#pragma unroll
    for (int k = 0; k < 9; ++k) R1[k] = make_float2(0.f, 0.f);
#pragma unroll
    for (int k = 0; k < 7; ++k) { R2[k] = make_float2(0.f, 0.f); R3[k] = make_float2(0.f, 0.f); }

    // prologue: stage first slice into raw[0]
    {
        const int s0 = z0 - 4;
        if (s0 >= 0 && s0 < D && tid < 240)
            st_task41(raw[0], tid, ld_task10(xs + (long long)s0 * DD, ty0 - 4, tx0 - 4, tid));
    }
    __syncthreads();

    int cur = 0;
    for (int s = z0 - 4; s < z0 + SEG + 4; ++s) {
        const bool inz = (s >= 0 && s < D);
        if (inz && tid < 192) {
            const int r = tid >> 3, g = tid & 7;
            const float* rp = &raw[cur][r * 41 + 4 * g];
            float win[12];
#pragma unroll
            for (int i = 0; i < 12; ++i) win[i] = rp[i];
            float4 o1 = make_float4(0.f, 0.f, 0.f, 0.f);
            float4 o2 = make_float4(0.f, 0.f, 0.f, 0.f);
#pragma unroll
            for (int k = 0; k < 5; ++k) {
                o1.x += czc[k] * win[2 + k];
                o1.y += czc[k] * win[3 + k];
                o1.z += czc[k] * win[4 + k];
                o1.w += czc[k] * win[5 + k];
            }
#pragma unroll
            for (int k = 0; k < 9; ++k) {
                o2.x += cxc[k] * win[k];
                o2.y += cxc[k] * win[1 + k];
                o2.z += cxc[k] * win[2 + k];
                o2.w += cxc[k] * win[3 + k];
            }
            *(float4*)&X1[cur][r][4 * g] = o1;
            *(float4*)&X2[cur][r][4 * g] = o2;
        }
        const int sn = s + 1;
        if (sn < z0 + SEG + 4 && sn >= 0 && sn < D && tid < 240)
            st_task41(raw[cur ^ 1], tid, ld_task10(xs + (long long)sn * DD, ty0 - 4, tx0 - 4, tid));
        __syncthreads();                       // X[cur] + raw[cur^1] ready
        float2 t1 = make_float2(0.f, 0.f), t2 = t1, t3 = t1;
        if (inz) {
#pragma unroll
            for (int k = 0; k < 5; ++k) {
                const float2 v = *(const float2*)&X1[cur][rr + 2 + k][cc];
                t1.x += bz[k] * v.x; t1.y += bz[k] * v.y;
            }
#pragma unroll
            for (int k = 0; k < 9; ++k) {
                const float2 v = *(const float2*)&X1[cur][rr + k][cc];
                t2.x += by[k] * v.x; t2.y += by[k] * v.y;
            }
#pragma unroll
            for (int k = 0; k < 5; ++k) {
                const float2 v = *(const float2*)&X2[cur][rr + 2 + k][cc];
                t3.x += bx[k] * v.x; t3.y += bx[k] * v.y;
            }
        }
#pragma unroll
        for (int k = 0; k < 8; ++k) R1[k] = R1[k + 1];
        R1[8] = t1;
#pragma unroll
        for (int k = 0; k < 6; ++k) { R2[k] = R2[k + 1]; R3[k] = R3[k + 1]; }
        R2[6] = t2; R3[6] = t3;
        const int z = s - 4;
        if (z >= z0) {
            float gz0 = 0.f, gz1 = 0.f, gy0 = 0.f, gy1 = 0.f, gx0 = 0.f, gx1 = 0.f;
#pragma unroll
            for (int k = 0; k < 9; ++k) { gz0 += az[k] * R1[k].x; gz1 += az[k] * R1[k].y; }
#pragma unroll
            for (int k = 0; k < 5; ++k) {
                gy0 += ay[k] * R2[k].x; gy1 += ay[k] * R2[k].y;
                gx0 += ax[k] * R3[k].x; gx1 += ax[k] * R3[k].y;
            }
            float* o = G + (long long)z * DD + (ty0 + rr) * D + tx0 + cc;
            float2 wv;
            wv.x = gz0; wv.y = gz1; *(float2*)(o + 0 * V) = wv;
            wv.x = gy0; wv.y = gy1; *(float2*)(o + 1 * V) = wv;
            wv.x = gx0; wv.y = gx1; *(float2*)(o + 2 * V) = wv;
        }
        cur ^= 1;
    }
}

extern "C" void kernel_launch(void* const* d_in, const int* in_sizes, int n_in,
                              void* d_out, int out_size, void* d_ws, size_t ws_size,
                              hipStream_t stream) {
    const float* x  = (const float*)d_in[0];
    const float* g3 = (const float*)d_in[1];
    const float* kz = (const float*)d_in[2];
    const float* ky = (const float*)d_in[3];
    const float* kx = (const float*)d_in[4];
    float* out = (float*)d_out;

    float* coef = (float*)d_ws;
    float* G  = coef + 128;          // 3*V floats (gz, gy, gx)
    float* xs = G + 3 * V;           // V floats

    setup_coef<<<1, 64, 0, stream>>>(g3, kz, ky, kx, coef);

    // S1: Gaussian pre-smooth  x -> xs   (72 tiles x 24 segs = 1728 blocks = 6.75/CU)
    blur3d_s1_db<8><<<1728, 256, 0, stream>>>(x, xs, coef);

    // S2: gradients  xs -> G[3]         (72 tiles x 24 segs = 1728 blocks = 6.75/CU)
    grad3d_db<8><<<1728, 256, 0, stream>>>(xs, G, coef);

    // S3: products-on-the-fly + grouped smoothing, dbuf, 1 barrier/slice
    //     (36 tiles x 6 ch x 8 segs = 1728 blocks = 6.75/CU, z-amp 1.25)
    blur3d_db<24, 6, true><<<1728, 256, 0, stream>>>(G, out, coef);
}

// Round 22
// 147.751 us; speedup vs baseline: 1.0277x; 1.0277x over previous
//
#include <hip/hip_runtime.h>

// 192^3 structure tensor, fused z-streaming pipeline (4 dispatches) — FINAL (r20 best):
//   S0: setup_coef        (extract 1D rank-1 factors from the provided 3D kernels)
//   S1: blur3d_s1_db<8>   x -> xs    (32x16 tile, float2 yconv, dbuf; 1728 blk = 6.75/CU)
//   S2: grad3d_db<12>     xs -> G[3] (dbuf; 1152 blk = 4.5/CU)
//   S3: blur3d_db<24,6>   G -> out   (products at staging + dbuf; 1728 blk = 6.75/CU)
// SEG optima measured r19-r21: S1=8, S2=12 (8 regressed: +20% work > +50% occ), S3=24.
// Proven LDS classes only: stride-41 b32 staging/sliding windows; stride-32 b128 xt
// (exact 8-row x 8-quad 1-row/thread map); float2/float4 stride-32 reads (1 row/thread).

constexpr int D  = 192;
constexpr int DD = D * D;                  // 36864
constexpr long long V = (long long)D * DD; // 7077888

// coef layout (floats):
//  [0..6] ga  [7..13] gb  [14..20] gc   (gauss z,y,x)
//  [21..29] az (9)  [30..34] bz (5)  [35..39] cz (5)
//  [40..44] ay (5)  [45..53] by (9)  [54..58] cy (5, dup)
//  [59..63] ax (5)  [64..68] bx (5)  [69..77] cx (9)
__global__ void setup_coef(const float* __restrict__ g3, const float* __restrict__ kz,
                           const float* __restrict__ ky, const float* __restrict__ kx,
                           float* __restrict__ c) {
    if (blockIdx.x != 0 || threadIdx.x != 0) return;
    float Tg = g3[0];
    for (int i = 0; i < 7; ++i) c[0 + i]  = g3[i * 49];
    for (int j = 0; j < 7; ++j) c[7 + j]  = g3[j * 7] / Tg;
    for (int k = 0; k < 7; ++k) c[14 + k] = g3[k] / Tg;
    float Tz = kz[0];                      // kz: [9,5,5]
    for (int i = 0; i < 9; ++i) c[21 + i] = kz[i * 25];
    for (int j = 0; j < 5; ++j) c[30 + j] = kz[j * 5] / Tz;
    for (int k = 0; k < 5; ++k) c[35 + k] = kz[k] / Tz;
    float Ty = ky[0];                      // ky: [5,9,5]
    for (int i = 0; i < 5; ++i) c[40 + i] = ky[i * 45];
    for (int j = 0; j < 9; ++j) c[45 + j] = ky[j * 5] / Ty;
    for (int k = 0; k < 5; ++k) c[54 + k] = ky[k] / Ty;
    float Tx = kx[0];                      // kx: [5,5,9]
    for (int i = 0; i < 5; ++i) c[59 + i] = kx[i * 45];
    for (int j = 0; j < 5; ++j) c[64 + j] = kx[j * 9] / Tx;
    for (int k = 0; k < 9; ++k) c[69 + k] = kx[k] / Tx;
}

// Bounds-checked float4 load from one z-slice (row gy, cols gx..gx+3), zero-padded.
__device__ inline float4 ldg4(const float* __restrict__ slice, int gy, int gx) {
    float4 v = {0.f, 0.f, 0.f, 0.f};
    if ((unsigned)gy < (unsigned)D) {
        const float* row = slice + gy * D;
        if ((unsigned)gx <= (unsigned)(D - 4)) {
            v = *(const float4*)(row + gx);
        } else {
            float* pv = (float*)&v;
#pragma unroll
            for (int j = 0; j < 4; ++j) {
                const int g = gx + j;
                if ((unsigned)g < (unsigned)D) pv[j] = row[g];
            }
        }
    }
    return v;
}

// Dual-field bounds-hoisted load: computes bounds once, loads A and B rows.
__device__ inline void ldg4x2(const float* __restrict__ slA, const float* __restrict__ slB,
                              int gy, int gx, float4& a, float4& b) {
    a = make_float4(0.f, 0.f, 0.f, 0.f);
    b = a;
    if ((unsigned)gy < (unsigned)D) {
        const int ro = gy * D;
        if ((unsigned)gx <= (unsigned)(D - 4)) {
            a = *(const float4*)(slA + ro + gx);
            b = *(const float4*)(slB + ro + gx);
        } else {
            float* pa = (float*)&a;
            float* pb = (float*)&b;
#pragma unroll
            for (int j = 0; j < 4; ++j) {
                const int g = gx + j;
                if ((unsigned)g < (unsigned)D) { pa[j] = slA[ro + g]; pb[j] = slB[ro + g]; }
            }
        }
    }
}

// Staging task li -> (row li/10, quad li%10) of a (rows x 40) region, stride-41 LDS.
__device__ inline float4 ld_task10(const float* __restrict__ slice, int y0, int x0, int li) {
    const int r = li / 10, q = li % 10;
    return ldg4(slice, y0 + r, x0 + q * 4);
}
__device__ inline void st_task41(float* __restrict__ dst, int li, float4 v) {
    const int r = li / 10, q = li % 10;
    float* d = &dst[r * 41 + q * 4];
    d[0] = v.x; d[1] = v.y; d[2] = v.z; d[3] = v.w;   // b32 class: conflict-free
}

// Stage one slice of (38 x 40) region into stride-41 LDS, with optional product fusion.
template <bool PROD>
__device__ inline void stage_s3(const float* __restrict__ slA, const float* __restrict__ slB,
                                bool same, float* __restrict__ dst, int ty0, int tx0) {
    if (same) {
        for (int li = threadIdx.x; li < 380; li += 256) {
            float4 a = ld_task10(slA, ty0 - 3, tx0 - 4, li);
            if (PROD) { a.x *= a.x; a.y *= a.y; a.z *= a.z; a.w *= a.w; }
            st_task41(dst, li, a);
        }
    } else {
        for (int li = threadIdx.x; li < 380; li += 256) {
            const int r = li / 10, q = li % 10;
            float4 a, b;
            ldg4x2(slA, slB, ty0 - 3 + r, tx0 - 4 + q * 4, a, b);
            a.x *= b.x; a.y *= b.y; a.z *= b.z; a.w *= b.w;
            float* d = &dst[r * 41 + q * 4];
            d[0] = a.x; d[1] = a.y; d[2] = a.z; d[3] = a.w;
        }
    }
}

// ---- S1: fused separable 3D blur, 32x16 tile, float2 yconv, double-buffered ----
template <int SEG>
__global__ __launch_bounds__(256) void blur3d_s1_db(const float* __restrict__ in,
                                                    float* __restrict__ out,
                                                    const float* __restrict__ coef) {
    __shared__ float raw[2][22 * 41];
    __shared__ float xt[2][22][32];
    const int cpx = gridDim.x >> 3;
    int w = (blockIdx.x & 7) * cpx + (blockIdx.x >> 3);
    const int tile = w % 72;
    const int seg = w / 72;
    const int tx0 = (tile % 6) * 32, ty0 = (tile / 6) * 16;
    const int z0 = seg * SEG;
    float ga[7], gb[7], gc[7];
#pragma unroll
    for (int k = 0; k < 7; ++k) { ga[k] = coef[k]; gb[k] = coef[7 + k]; gc[k] = coef[14 + k]; }
    const int tid = threadIdx.x;
    const int rr = tid >> 4;                   // 0..15 (yconv rows)
    const int cc = (tid & 15) * 2;             // 0,2,..,30
    float2 ring[7];
#pragma unroll
    for (int k = 0; k < 7; ++k) ring[k] = make_float2(0.f, 0.f);

    // prologue: stage first slice into raw[0]
    {
        const int s0 = z0 - 3;
        if (s0 >= 0 && s0 < D && tid < 220)
            st_task41(raw[0], tid, ld_task10(in + (long long)s0 * DD, ty0 - 3, tx0 - 4, tid));
    }
    __syncthreads();

    int cur = 0;
    for (int s = z0 - 3; s < z0 + SEG + 3; ++s) {
        const bool inz = (s >= 0 && s < D);
        if (inz && tid < 176) {
            const int r = tid >> 3, g = tid & 7;
            const float* rp = &raw[cur][r * 41 + 4 * g + 1];
            float win[10];
#pragma unroll
            for (int i = 0; i < 10; ++i) win[i] = rp[i];
            float4 o = make_float4(0.f, 0.f, 0.f, 0.f);
#pragma unroll
            for (int k = 0; k < 7; ++k) {
                o.x += gc[k] * win[k];
                o.y += gc[k] * win[k + 1];
                o.z += gc[k] * win[k + 2];
                o.w += gc[k] * win[k + 3];
            }
            *(float4*)&xt[cur][r][4 * g] = o;
        }
        const int sn = s + 1;
        if (sn < z0 + SEG + 3 && sn >= 0 && sn < D && tid < 220)
            st_task41(raw[cur ^ 1], tid, ld_task10(in + (long long)sn * DD, ty0 - 3, tx0 - 4, tid));
        __syncthreads();                       // xt[cur] + raw[cur^1] ready
        float2 yv = make_float2(0.f, 0.f);
        if (inz) {
#pragma unroll
            for (int k = 0; k < 7; ++k) {
                const float2 v = *(const float2*)&xt[cur][rr + k][cc];
                yv.x += gb[k] * v.x; yv.y += gb[k] * v.y;
            }
        }
#pragma unroll
        for (int k = 0; k < 6; ++k) ring[k] = ring[k + 1];
        ring[6] = yv;
        const int z = s - 3;
        if (z >= z0) {
            float2 a = make_float2(0.f, 0.f);
#pragma unroll
            for (int k = 0; k < 7; ++k) {
                a.x += ga[k] * ring[k].x; a.y += ga[k] * ring[k].y;
            }
            *(float2*)(out + (long long)z * DD + (ty0 + rr) * D + tx0 + cc) = a;
        }
        cur ^= 1;
    }
}

// ---- S3: double-buffered product blur, 32x32 tile, 1 barrier/slice (r16-proven) ----
template <int SEG, int NCH, bool PROD>
__global__ __launch_bounds__(256) void blur3d_db(const float* __restrict__ in,
                                                 float* __restrict__ out,
                                                 const float* __restrict__ coef) {
    __shared__ float raw[2][38 * 41];
    __shared__ float xt[2][38][32];
    const int cpx = gridDim.x >> 3;
    int w = (blockIdx.x & 7) * cpx + (blockIdx.x >> 3);
    const int tile = w % 36; w /= 36;
    const int ch = w % NCH;
    const int seg = w / NCH;
    const int tx0 = (tile % 6) * 32, ty0 = (tile / 6) * 32;
    const int z0 = seg * SEG;
    // product channel -> gradient-field pair: [Jzz,Jzy,Jzx,Jyy,Jyx,Jxx]
    const int IA[6] = {0, 1, 2, 1, 2, 2};
    const int IB[6] = {0, 0, 0, 1, 1, 2};
    const float* srcA = in + (long long)(PROD ? IA[ch] : ch) * V;
    const float* srcB = in + (long long)(PROD ? IB[ch] : ch) * V;
    const bool same = !PROD || (IA[ch] == IB[ch]);
    float* dst = out + (long long)ch * V;
    float ga[7], gb[7], gc[7];
#pragma unroll
    for (int k = 0; k < 7; ++k) { ga[k] = coef[k]; gb[k] = coef[7 + k]; gc[k] = coef[14 + k]; }
    const int tid = threadIdx.x;
    const int rr = tid >> 3;                  // 0..31
    const int cc = (tid & 7) * 4;             // 0,4,..,28
    float4 ring[7];
#pragma unroll
    for (int k = 0; k < 7; ++k) ring[k] = make_float4(0.f, 0.f, 0.f, 0.f);

    // prologue: stage first slice into raw[0]
    {
        const int s0 = z0 - 3;
        if (s0 >= 0 && s0 < D)
            stage_s3<PROD>(srcA + (long long)s0 * DD, srcB + (long long)s0 * DD,
                           same, raw[0], ty0, tx0);
    }
    __syncthreads();

    int cur = 0;
    for (int s = z0 - 3; s < z0 + SEG + 3; ++s) {
        const bool inz = (s >= 0 && s < D);
        // phase a: xconv slice s from raw[cur] into xt[cur]
        if (inz) {
            for (int li = tid; li < 38 * 8; li += 256) {
                const int r = li >> 3, g = li & 7;
                const float* rp = &raw[cur][r * 41 + 4 * g + 1];
                float win[10];
#pragma unroll
                for (int i = 0; i < 10; ++i) win[i] = rp[i];
                float4 o = make_float4(0.f, 0.f, 0.f, 0.f);
#pragma unroll
                for (int k = 0; k < 7; ++k) {
                    o.x += gc[k] * win[k];
                    o.y += gc[k] * win[k + 1];
                    o.z += gc[k] * win[k + 2];
                    o.w += gc[k] * win[k + 3];
                }
                *(float4*)&xt[cur][r][4 * g] = o;
            }
        }
        // phase b: stage slice s+1 into raw[cur^1]
        const int sn = s + 1;
        if (sn < z0 + SEG + 3 && sn >= 0 && sn < D)
            stage_s3<PROD>(srcA + (long long)sn * DD, srcB + (long long)sn * DD,
                           same, raw[cur ^ 1], ty0, tx0);
        __syncthreads();                      // xt[cur] + raw[cur^1] ready
        // phase d: yconv slice s from xt[cur], ring, store
        float4 yv = make_float4(0.f, 0.f, 0.f, 0.f);
        if (inz) {
#pragma unroll
            for (int k = 0; k < 7; ++k) {
                const float4 v = *(const float4*)&xt[cur][rr + k][cc];
                yv.x += gb[k] * v.x; yv.y += gb[k] * v.y;
                yv.z += gb[k] * v.z; yv.w += gb[k] * v.w;
            }
        }
#pragma unroll
        for (int k = 0; k < 6; ++k) ring[k] = ring[k + 1];
        ring[6] = yv;
        const int z = s - 3;
        if (z >= z0) {
            float4 a = make_float4(0.f, 0.f, 0.f, 0.f);
#pragma unroll
            for (int k = 0; k < 7; ++k) {
                a.x += ga[k] * ring[k].x; a.y += ga[k] * ring[k].y;
                a.z += ga[k] * ring[k].z; a.w += ga[k] * ring[k].w;
            }
            *(float4*)(dst + (long long)z * DD + (ty0 + rr) * D + tx0 + cc) = a;
        }
        cur ^= 1;
    }
}

// ---- S2: fused gradients, 32x16 tile, register rings, double-buffered ----
template <int SEG>
__global__ __launch_bounds__(256) void grad3d_db(const float* __restrict__ xs,
                                                 float* __restrict__ G,
                                                 const float* __restrict__ coef) {
    __shared__ float raw[2][24 * 41];
    __shared__ float X1[2][24][32];
    __shared__ float X2[2][24][32];
    const int cpx = gridDim.x >> 3;
    int w = (blockIdx.x & 7) * cpx + (blockIdx.x >> 3);
    const int tile = w % 72;
    const int seg = w / 72;
    const int tx0 = (tile % 6) * 32, ty0 = (tile / 6) * 16;
    const int z0 = seg * SEG;
    float az[9], ay[5], ax[5], bz[5], by[9], bx[5], czc[5], cxc[9];
#pragma unroll
    for (int k = 0; k < 9; ++k) az[k] = coef[21 + k];
#pragma unroll
    for (int k = 0; k < 5; ++k) ay[k] = coef[40 + k];
#pragma unroll
    for (int k = 0; k < 5; ++k) ax[k] = coef[59 + k];
#pragma unroll
    for (int k = 0; k < 5; ++k) bz[k] = coef[30 + k];
#pragma unroll
    for (int k = 0; k < 9; ++k) by[k] = coef[45 + k];
#pragma unroll
    for (int k = 0; k < 5; ++k) bx[k] = coef[64 + k];
#pragma unroll
    for (int k = 0; k < 5; ++k) czc[k] = coef[35 + k];
#pragma unroll
    for (int k = 0; k < 9; ++k) cxc[k] = coef[69 + k];
    const int tid = threadIdx.x;
    const int rr = tid >> 4;                   // 0..15
    const int cc = (tid & 15) * 2;             // 0,2,..,30
    float2 R1[9], R2[7], R3[7];
#pragma unroll
    for (int k = 0; k < 9; ++k) R1[k] = make_float2(0.f, 0.f);
#pragma unroll
    for (int k = 0; k < 7; ++k) { R2[k] = make_float2(0.f, 0.f); R3[k] = make_float2(0.f, 0.f); }

    // prologue: stage first slice into raw[0]
    {
        const int s0 = z0 - 4;
        if (s0 >= 0 && s0 < D && tid < 240)
            st_task41(raw[0], tid, ld_task10(xs + (long long)s0 * DD, ty0 - 4, tx0 - 4, tid));
    }
    __syncthreads();

    int cur = 0;
    for (int s = z0 - 4; s < z0 + SEG + 4; ++s) {
        const bool inz = (s >= 0 && s < D);
        if (inz && tid < 192) {
            const int r = tid >> 3, g = tid & 7;
            const float* rp = &raw[cur][r * 41 + 4 * g];
            float win[12];
#pragma unroll
            for (int i = 0; i < 12; ++i) win[i] = rp[i];
            float4 o1 = make_float4(0.f, 0.f, 0.f, 0.f);
            float4 o2 = make_float4(0.f, 0.f, 0.f, 0.f);
#pragma unroll
            for (int k = 0; k < 5; ++k) {
                o1.x += czc[k] * win[2 + k];
                o1.y += czc[k] * win[3 + k];
                o1.z += czc[k] * win[4 + k];
                o1.w += czc[k] * win[5 + k];
            }
#pragma unroll
            for (int k = 0; k < 9; ++k) {
                o2.x += cxc[k] * win[k];
                o2.y += cxc[k] * win[1 + k];
                o2.z += cxc[k] * win[2 + k];
                o2.w += cxc[k] * win[3 + k];
            }
            *(float4*)&X1[cur][r][4 * g] = o1;
            *(float4*)&X2[cur][r][4 * g] = o2;
        }
        const int sn = s + 1;
        if (sn < z0 + SEG + 4 && sn >= 0 && sn < D && tid < 240)
            st_task41(raw[cur ^ 1], tid, ld_task10(xs + (long long)sn * DD, ty0 - 4, tx0 - 4, tid));
        __syncthreads();                       // X[cur] + raw[cur^1] ready
        float2 t1 = make_float2(0.f, 0.f), t2 = t1, t3 = t1;
        if (inz) {
#pragma unroll
            for (int k = 0; k < 5; ++k) {
                const float2 v = *(const float2*)&X1[cur][rr + 2 + k][cc];
                t1.x += bz[k] * v.x; t1.y += bz[k] * v.y;
            }
#pragma unroll
            for (int k = 0; k < 9; ++k) {
                const float2 v = *(const float2*)&X1[cur][rr + k][cc];
                t2.x += by[k] * v.x; t2.y += by[k] * v.y;
            }
#pragma unroll
            for (int k = 0; k < 5; ++k) {
                const float2 v = *(const float2*)&X2[cur][rr + 2 + k][cc];
                t3.x += bx[k] * v.x; t3.y += bx[k] * v.y;
            }
        }
#pragma unroll
        for (int k = 0; k < 8; ++k) R1[k] = R1[k + 1];
        R1[8] = t1;
#pragma unroll
        for (int k = 0; k < 6; ++k) { R2[k] = R2[k + 1]; R3[k] = R3[k + 1]; }
        R2[6] = t2; R3[6] = t3;
        const int z = s - 4;
        if (z >= z0) {
            float gz0 = 0.f, gz1 = 0.f, gy0 = 0.f, gy1 = 0.f, gx0 = 0.f, gx1 = 0.f;
#pragma unroll
            for (int k = 0; k < 9; ++k) { gz0 += az[k] * R1[k].x; gz1 += az[k] * R1[k].y; }
#pragma unroll
            for (int k = 0; k < 5; ++k) {
                gy0 += ay[k] * R2[k].x; gy1 += ay[k] * R2[k].y;
                gx0 += ax[k] * R3[k].x; gx1 += ax[k] * R3[k].y;
            }
            float* o = G + (long long)z * DD + (ty0 + rr) * D + tx0 + cc;
            float2 wv;
            wv.x = gz0; wv.y = gz1; *(float2*)(o + 0 * V) = wv;
            wv.x = gy0; wv.y = gy1; *(float2*)(o + 1 * V) = wv;
            wv.x = gx0; wv.y = gx1; *(float2*)(o + 2 * V) = wv;
        }
        cur ^= 1;
    }
}

extern "C" void kernel_launch(void* const* d_in, const int* in_sizes, int n_in,
                              void* d_out, int out_size, void* d_ws, size_t ws_size,
                              hipStream_t stream) {
    const float* x  = (const float*)d_in[0];
    const float* g3 = (const float*)d_in[1];
    const float* kz = (const float*)d_in[2];
    const float* ky = (const float*)d_in[3];
    const float* kx = (const float*)d_in[4];
    float* out = (float*)d_out;

    float* coef = (float*)d_ws;
    float* G  = coef + 128;          // 3*V floats (gz, gy, gx)
    float* xs = G + 3 * V;           // V floats

    setup_coef<<<1, 64, 0, stream>>>(g3, kz, ky, kx, coef);

    // S1: Gaussian pre-smooth  x -> xs   (72 tiles x 24 segs = 1728 blocks = 6.75/CU)
    blur3d_s1_db<8><<<1728, 256, 0, stream>>>(x, xs, coef);

    // S2: gradients  xs -> G[3]         (72 tiles x 16 segs = 1152 blocks = 4.5/CU)
    grad3d_db<12><<<1152, 256, 0, stream>>>(xs, G, coef);

    // S3: products-on-the-fly + grouped smoothing, dbuf, 1 barrier/slice
    //     (36 tiles x 6 ch x 8 segs = 1728 blocks = 6.75/CU, z-amp 1.25)
    blur3d_db<24, 6, true><<<1728, 256, 0, stream>>>(G, out, coef);
}